// Round 7
// baseline (256.209 us; speedup 1.0000x reference)
//
#include <hip/hip_runtime.h>
#include <math.h>

// Router: logits = z @ W^T + b ; top-2 sparse softmax.  z:[8192,4096]f32,
// W:[64,4096]f32, b:[64], k=2.
//
// R7 = R6 with the pointer-arithmetic precedence fix (the only change:
// ((size_t)24 << 20) parenthesized). Theory unchanged:
// R4/R5 post-mortem showed a ~75us constant insensitive to LDS traffic
// and occupancy -> suspects: z-stripe latency (H1) and barrier/LDS-queue
// cost per chunk (H2). W pre-converted once to f16 hi/lo limbs in d_ws
// (frag-layout, L1/L2-resident) and read as B-fragments DIRECTLY from
// global in the MFMA loop (no W LDS, no W convert in-loop); CH=128
// (512B z stripes, 8 barriers/block); KQ=8 -> grid 1024, 3 blocks/CU
// (launch_bounds(512,6)), 24 waves/CU; prefetch issued pre-barrier.
// Precision: fp16 2-limb (x = h + l*2^-11, l prescaled 2^11), 3 MFMA passes
// -> fp32-class logit error; identical math to the passing R5.
// Frag layouts (verified R4/R5): A[m=lane&15][k=quad*8+j],
// B[n=lane&15][k=quad*8+j], D[row=quad*4+reg][col=lane&15].

typedef _Float16 f16x8 __attribute__((ext_vector_type(8)));
typedef _Float16 f16x4 __attribute__((ext_vector_type(4)));
typedef float    f32x4 __attribute__((ext_vector_type(4)));

constexpr int D_DIM  = 4096;
constexpr int K_DIM  = 64;
constexpr int BM     = 64;             // rows per block
constexpr int CH     = 128;            // k per staged chunk
constexpr int KQ     = 8;              // split-K across blocks
constexpr int KRANGE = D_DIM / KQ;     // 512
constexpr int NCH    = KRANGE / CH;    // 4
constexpr int BLOCK  = 512;
constexpr int LSTR   = 136;            // z limb row stride in f16 (272 B, 16B-aligned)

// ---- prep: W (fp32) -> f16 hi/lo limb planes in d_ws, layout [n][k] -------
__global__ __launch_bounds__(256) void prep_w(
    const float* __restrict__ W, _Float16* __restrict__ Wf0,
    _Float16* __restrict__ Wf1)
{
    int f = blockIdx.x * 256 + threadIdx.x;          // float4 index, 65536 total
    const float4 v = *(const float4*)(W + (long)f * 4);
    const float* p = (const float*)&v;
    f16x4 h, l;
#pragma unroll
    for (int j = 0; j < 4; ++j) {
        _Float16 hh = (_Float16)p[j];
        h[j] = hh;
        l[j] = (_Float16)((p[j] - (float)hh) * 2048.0f);
    }
    *(f16x4*)(Wf0 + (long)f * 4) = h;
    *(f16x4*)(Wf1 + (long)f * 4) = l;
}

// ---- gemm: z via LDS limbs, W frags direct from global --------------------
__global__ __launch_bounds__(BLOCK, 6) void gemm_f16limb(
    const float* __restrict__ z, const _Float16* __restrict__ Wf0,
    const _Float16* __restrict__ Wf1, float* __restrict__ part, int N)
{
    __shared__ __align__(16) _Float16 Az[2][BM][LSTR];   // 34.8 KB

    const int tid  = threadIdx.x;
    const int lane = tid & 63;
    const int wv   = tid >> 6;          // 0..7
    const int mt   = wv >> 1;           // m-tile 0..3 (16 rows)
    const int nh   = wv & 1;            // n-half (2 n-tiles each)
    const int m16  = lane & 15;
    const int quad = lane >> 4;

    const int rgrp  = blockIdx.x >> 3;  // row group of 64
    const int kq    = blockIdx.x & 7;
    const long m0   = (long)rgrp * BM;
    const int kbase = kq * KRANGE;

    float4 zb[4];
#pragma unroll
    for (int i = 0; i < 4; ++i) {
        int f = tid + i * BLOCK, r = f >> 5, c4 = (f & 31) * 4;
        zb[i] = *(const float4*)(z + (m0 + r) * (long)D_DIM + kbase + c4);
    }

    f32x4 acch[2], accl[2];
#pragma unroll
    for (int t = 0; t < 2; ++t) {
        acch[t] = (f32x4){0.f, 0.f, 0.f, 0.f};
        accl[t] = (f32x4){0.f, 0.f, 0.f, 0.f};
    }

    for (int ch = 0; ch < NCH; ++ch) {
        // convert current z regs -> 2 fp16 limb planes in LDS (lo *2^11)
#pragma unroll
        for (int i = 0; i < 4; ++i) {
            int f = tid + i * BLOCK, r = f >> 5, c4 = (f & 31) * 4;
            const float* p = (const float*)&zb[i];
            f16x4 h, l;
#pragma unroll
            for (int j = 0; j < 4; ++j) {
                _Float16 hh = (_Float16)p[j];
                h[j] = hh;
                l[j] = (_Float16)((p[j] - (float)hh) * 2048.0f);
            }
            *(f16x4*)&Az[0][r][c4] = h;
            *(f16x4*)&Az[1][r][c4] = l;
        }
        // prefetch next chunk BEFORE the barrier: loads stay in flight
        // across barrier + MFMA phase (few regs, fenced -> no hoist/spill)
        if (ch + 1 < NCH) {
            const int k0 = kbase + (ch + 1) * CH;
#pragma unroll
            for (int i = 0; i < 4; ++i) {
                int f = tid + i * BLOCK, r = f >> 5, c4 = (f & 31) * 4;
                zb[i] = *(const float4*)(z + (m0 + r) * (long)D_DIM + k0 + c4);
            }
        }
        __syncthreads();

        const int mrow = mt * 16 + m16;
#pragma unroll
        for (int ks2 = 0; ks2 < 4; ++ks2) {
            const int klocal = ks2 * 32 + quad * 8;
            const long kglob = kbase + ch * CH + klocal;
            const f16x8 ah = *(const f16x8*)&Az[0][mrow][klocal];
            const f16x8 al = *(const f16x8*)&Az[1][mrow][klocal];
#pragma unroll
            for (int t = 0; t < 2; ++t) {
                const int n = (nh * 2 + t) * 16 + m16;
                const f16x8 bh = *(const f16x8*)(Wf0 + (long)n * D_DIM + kglob);
                const f16x8 bl = *(const f16x8*)(Wf1 + (long)n * D_DIM + kglob);
                accl[t] = __builtin_amdgcn_mfma_f32_16x16x32_f16(al, bh, accl[t], 0, 0, 0);
                accl[t] = __builtin_amdgcn_mfma_f32_16x16x32_f16(ah, bl, accl[t], 0, 0, 0);
                acch[t] = __builtin_amdgcn_mfma_f32_16x16x32_f16(ah, bh, acch[t], 0, 0, 0);
            }
        }
        __syncthreads();
    }

    // partial store: D[row=quad*4+r][col], recombine limbs (*2^-11)
#pragma unroll
    for (int t = 0; t < 2; ++t) {
#pragma unroll
        for (int r = 0; r < 4; ++r) {
            long row = m0 + mt * 16 + quad * 4 + r;
            int  col = (nh * 2 + t) * 16 + m16;
            part[((long)kq * N + row) * K_DIM + col] =
                acch[t][r] + accl[t][r] * 4.8828125e-4f;
        }
    }
}

// ---- reduce + bias + top-2 + sparse softmax -------------------------------
constexpr int RG2  = 32;
constexpr int BLK2 = 256;

__global__ __launch_bounds__(BLK2) void reduce_topk(
    const float* __restrict__ part, const float* __restrict__ bias,
    float* __restrict__ out, int N)
{
    __shared__ float lg[RG2][K_DIM + 1];
    __shared__ float sa1[RG2], sa2[RG2];
    __shared__ int   si1[RG2], si2[RG2];

    const int tid = threadIdx.x;
    const long r0 = (long)blockIdx.x * RG2;

#pragma unroll
    for (int i = 0; i < (RG2 * K_DIM) / (BLK2 * 4); ++i) {       // 2 iters
        int f = tid + i * BLK2, r = f >> 4, c4 = (f & 15) * 4;
        float4 s = *(const float4*)(part + (r0 + r) * K_DIM + c4);
#pragma unroll
        for (int q = 1; q < KQ; ++q) {
            const float4 v = *(const float4*)(part + ((long)q * N + r0 + r) * K_DIM + c4);
            s.x += v.x; s.y += v.y; s.z += v.z; s.w += v.w;
        }
        const float4 bv = *(const float4*)(bias + c4);
        lg[r][c4 + 0] = s.x + bv.x;
        lg[r][c4 + 1] = s.y + bv.y;
        lg[r][c4 + 2] = s.z + bv.z;
        lg[r][c4 + 3] = s.w + bv.w;
    }
    __syncthreads();

    if (tid < RG2) {   // strict >, ascending scan = lowest-index tie-break
        float m1 = -INFINITY, m2 = -INFINITY;
        int i1 = 0, i2 = 0;
        for (int j = 0; j < K_DIM; ++j) {
            float v = lg[tid][j];
            if (v > m1)      { m2 = m1; i2 = i1; m1 = v; i1 = j; }
            else if (v > m2) { m2 = v; i2 = j; }
        }
        float e2  = expf(m2 - m1);
        float inv = 1.f / (1.f + e2);
        sa1[tid] = inv; sa2[tid] = e2 * inv;
        si1[tid] = i1;  si2[tid] = i2;
    }
    __syncthreads();

    float* obase = out + r0 * K_DIM;
#pragma unroll
    for (int i = 0; i < (RG2 * K_DIM) / (BLK2 * 4); ++i) {       // 2 iters
        int f = tid + i * BLK2, r = f >> 4, j = (f & 15) * 4;
        int i1 = si1[r], i2 = si2[r];
        float a1 = sa1[r], a2 = sa2[r];
        float4 v;
        v.x = (j + 0 == i1) ? a1 : ((j + 0 == i2) ? a2 : 0.f);
        v.y = (j + 1 == i1) ? a1 : ((j + 1 == i2) ? a2 : 0.f);
        v.z = (j + 2 == i1) ? a1 : ((j + 2 == i2) ? a2 : 0.f);
        v.w = (j + 3 == i1) ? a1 : ((j + 3 == i2) ? a2 : 0.f);
        *(float4*)(obase + (long)r * K_DIM + j) = v;
    }
}

extern "C" void kernel_launch(void* const* d_in, const int* in_sizes, int n_in,
                              void* d_out, int out_size, void* d_ws, size_t ws_size,
                              hipStream_t stream) {
    const float* z = (const float*)d_in[0];
    const float* W = (const float*)d_in[1];
    const float* b = (const float*)d_in[2];
    float* out  = (float*)d_out;
    const int N = in_sizes[0] / D_DIM;           // 8192

    float*    part = (float*)d_ws;                                  // 16 MB
    _Float16* Wf0  = (_Float16*)((char*)d_ws + ((size_t)24 << 20)); // 512 KB
    _Float16* Wf1  = Wf0 + (size_t)K_DIM * D_DIM;                   // 512 KB

    prep_w      <<<dim3((K_DIM * D_DIM / 4) / 256), dim3(256), 0, stream>>>(W, Wf0, Wf1);
    gemm_f16limb<<<dim3((N / BM) * KQ), dim3(BLOCK), 0, stream>>>(z, Wf0, Wf1, part, N);
    reduce_topk <<<dim3(N / RG2),       dim3(BLK2), 0, stream>>>(part, b, out, N);
}

// Round 8
// 215.407 us; speedup vs baseline: 1.1894x; 1.1894x over previous
//
#include <hip/hip_runtime.h>
#include <math.h>

// Router: logits = z @ W^T + b ; top-2 sparse softmax.  z:[8192,4096]f32,
// W:[64,4096]f32, b:[64], k=2.
//
// R8: barrier-free K-loop. R7 post-mortem: all pipes idle (VALU 4%, MFMA 4%,
// HBM 15%) -> chunk cycle convert/barrier/compute/barrier serialized every
// wave on the slowest memory op; W global B-frags were 16-segment gathers
// inside the MFMA dependency chain at 40 VGPRs of load budget.
// Now: A-frags of z loaded DIRECTLY from global into registers (lane reads
// its own 32B frag; per-wave = 16 rows x 128B contiguous), converted
// in-register to fp16 hi/lo limbs -> no z LDS, no in-loop barriers; 16
// independent waves/CU stream with a 2-deep pipeline. W limbs (prep_w, once)
// staged to LDS ONCE per block (67.6 KB, KQ=16 slice; stride 264 f16 == 4
// words mod 32 -> 2-way frag reads, free); exactly one __syncthreads total.
// launch_bounds(512,4) caps VGPR<=128 -> 2 blocks/CU = 16 waves/CU.
// Precision identical to passing R5/R7: x = h + l*2^-11 (l prescaled), 3
// MFMA passes, recombine *2^-11 -> fp32-class logit error.
// Frag layouts (verified R4-R7): A[m=lane&15][k=quad*8+j],
// B[n=lane&15][k=quad*8+j], D[row=quad*4+reg][col=lane&15].

typedef _Float16 f16x8 __attribute__((ext_vector_type(8)));
typedef _Float16 f16x4 __attribute__((ext_vector_type(4)));
typedef float    f32x4 __attribute__((ext_vector_type(4)));

constexpr int D_DIM  = 4096;
constexpr int K_DIM  = 64;
constexpr int BM     = 128;            // rows per block (8 waves x 16)
constexpr int KQ     = 16;             // split-K across blocks
constexpr int KRANGE = D_DIM / KQ;     // 256
constexpr int BLOCK  = 512;
constexpr int BSTR   = 264;            // W limb row stride in f16 (528 B)

// ---- prep: W (fp32) -> f16 hi/lo limb planes in d_ws, layout [n][k] -------
__global__ __launch_bounds__(256) void prep_w(
    const float* __restrict__ W, _Float16* __restrict__ Wf0,
    _Float16* __restrict__ Wf1)
{
    int f = blockIdx.x * 256 + threadIdx.x;          // float4 index, 65536 total
    const float4 v = *(const float4*)(W + (long)f * 4);
    const float* p = (const float*)&v;
    f16x4 h, l;
#pragma unroll
    for (int j = 0; j < 4; ++j) {
        _Float16 hh = (_Float16)p[j];
        h[j] = hh;
        l[j] = (_Float16)((p[j] - (float)hh) * 2048.0f);
    }
    *(f16x4*)(Wf0 + (long)f * 4) = h;
    *(f16x4*)(Wf1 + (long)f * 4) = l;
}

// ---- gemm: z A-frags direct from global, W limbs in LDS, one barrier ------
__global__ __launch_bounds__(BLOCK, 4) void gemm_nobar(
    const float* __restrict__ z, const _Float16* __restrict__ Wf0,
    const _Float16* __restrict__ Wf1, float* __restrict__ part, int N)
{
    __shared__ __align__(16) _Float16 Bs[2][K_DIM][BSTR];   // 67.6 KB

    const int tid  = threadIdx.x;
    const int lane = tid & 63;
    const int wv   = tid >> 6;          // 0..7 = m-tile (16 rows each)
    const int m16  = lane & 15;
    const int quad = lane >> 4;

    const int rgrp  = blockIdx.x >> 4;  // row group of 128
    const int kq    = blockIdx.x & 15;
    const long m0   = (long)rgrp * BM;
    const int kbase = kq * KRANGE;

    // stage W limb slice once: 2 planes x 64 rows x 256 f16 (4096 x 16B)
#pragma unroll
    for (int i = 0; i < 8; ++i) {
        int f  = tid + i * BLOCK;
        int p  = f >> 11;               // plane (i<4 -> 0, else 1)
        int rr = (f >> 5) & 63;
        int c  = f & 31;
        const _Float16* src = (p ? Wf1 : Wf0) + (long)rr * D_DIM + kbase + c * 8;
        *(f16x8*)&Bs[p][rr][c * 8] = *(const f16x8*)src;
    }
    __syncthreads();                    // the only barrier

    const float* zp = z + (m0 + wv * 16 + m16) * (long)D_DIM + kbase;

    f32x4 acch[4], accl[4];
#pragma unroll
    for (int nt = 0; nt < 4; ++nt) {
        acch[nt] = (f32x4){0.f, 0.f, 0.f, 0.f};
        accl[nt] = (f32x4){0.f, 0.f, 0.f, 0.f};
    }

    float4 za[2][2];                    // 2-deep pipeline, 32 B/lane/step
    za[0][0] = *(const float4*)(zp + quad * 8);
    za[0][1] = *(const float4*)(zp + quad * 8 + 4);

#pragma unroll
    for (int s = 0; s < KRANGE / 32; ++s) {      // 8 ks-steps, no barriers
        const int cur = s & 1;
        if (s + 1 < KRANGE / 32) {
            za[cur ^ 1][0] = *(const float4*)(zp + (s + 1) * 32 + quad * 8);
            za[cur ^ 1][1] = *(const float4*)(zp + (s + 1) * 32 + quad * 8 + 4);
        }
        f16x8 ah, al;
        const float* pz = (const float*)&za[cur][0];
#pragma unroll
        for (int j = 0; j < 8; ++j) {
            _Float16 hh = (_Float16)pz[j];
            ah[j] = hh;
            al[j] = (_Float16)((pz[j] - (float)hh) * 2048.0f);
        }
        const int ko = s * 32 + quad * 8;
#pragma unroll
        for (int nt = 0; nt < 4; ++nt) {
            const f16x8 bh = *(const f16x8*)&Bs[0][nt * 16 + m16][ko];
            const f16x8 bl = *(const f16x8*)&Bs[1][nt * 16 + m16][ko];
            accl[nt] = __builtin_amdgcn_mfma_f32_16x16x32_f16(al, bh, accl[nt], 0, 0, 0);
            accl[nt] = __builtin_amdgcn_mfma_f32_16x16x32_f16(ah, bl, accl[nt], 0, 0, 0);
            acch[nt] = __builtin_amdgcn_mfma_f32_16x16x32_f16(ah, bh, acch[nt], 0, 0, 0);
        }
    }

    // partial store: D[row=quad*4+r][col=m16], recombine limbs (*2^-11)
#pragma unroll
    for (int nt = 0; nt < 4; ++nt) {
#pragma unroll
        for (int r = 0; r < 4; ++r) {
            long row = m0 + wv * 16 + quad * 4 + r;
            part[((long)kq * N + row) * K_DIM + nt * 16 + m16] =
                acch[nt][r] + accl[nt][r] * 4.8828125e-4f;
        }
    }
}

// ---- reduce + bias + top-2 + sparse softmax -------------------------------
constexpr int RG2  = 32;
constexpr int BLK2 = 256;

__global__ __launch_bounds__(BLK2) void reduce_topk(
    const float* __restrict__ part, const float* __restrict__ bias,
    float* __restrict__ out, int N)
{
    __shared__ float lg[RG2][K_DIM + 1];
    __shared__ float sa1[RG2], sa2[RG2];
    __shared__ int   si1[RG2], si2[RG2];

    const int tid = threadIdx.x;
    const long r0 = (long)blockIdx.x * RG2;

#pragma unroll
    for (int i = 0; i < (RG2 * K_DIM) / (BLK2 * 4); ++i) {       // 2 iters
        int f = tid + i * BLK2, r = f >> 4, c4 = (f & 15) * 4;
        float4 s = *(const float4*)(part + (r0 + r) * K_DIM + c4);
#pragma unroll
        for (int q = 1; q < KQ; ++q) {
            const float4 v = *(const float4*)(part + ((long)q * N + r0 + r) * K_DIM + c4);
            s.x += v.x; s.y += v.y; s.z += v.z; s.w += v.w;
        }
        const float4 bv = *(const float4*)(bias + c4);
        lg[r][c4 + 0] = s.x + bv.x;
        lg[r][c4 + 1] = s.y + bv.y;
        lg[r][c4 + 2] = s.z + bv.z;
        lg[r][c4 + 3] = s.w + bv.w;
    }
    __syncthreads();

    if (tid < RG2) {   // strict >, ascending scan = lowest-index tie-break
        float m1 = -INFINITY, m2 = -INFINITY;
        int i1 = 0, i2 = 0;
        for (int j = 0; j < K_DIM; ++j) {
            float v = lg[tid][j];
            if (v > m1)      { m2 = m1; i2 = i1; m1 = v; i1 = j; }
            else if (v > m2) { m2 = v; i2 = j; }
        }
        float e2  = expf(m2 - m1);
        float inv = 1.f / (1.f + e2);
        sa1[tid] = inv; sa2[tid] = e2 * inv;
        si1[tid] = i1;  si2[tid] = i2;
    }
    __syncthreads();

    float* obase = out + r0 * K_DIM;
#pragma unroll
    for (int i = 0; i < (RG2 * K_DIM) / (BLK2 * 4); ++i) {       // 2 iters
        int f = tid + i * BLK2, r = f >> 4, j = (f & 15) * 4;
        int i1 = si1[r], i2 = si2[r];
        float a1 = sa1[r], a2 = sa2[r];
        float4 v;
        v.x = (j + 0 == i1) ? a1 : ((j + 0 == i2) ? a2 : 0.f);
        v.y = (j + 1 == i1) ? a1 : ((j + 1 == i2) ? a2 : 0.f);
        v.z = (j + 2 == i1) ? a1 : ((j + 2 == i2) ? a2 : 0.f);
        v.w = (j + 3 == i1) ? a1 : ((j + 3 == i2) ? a2 : 0.f);
        *(float4*)(obase + (long)r * K_DIM + j) = v;
    }
}

extern "C" void kernel_launch(void* const* d_in, const int* in_sizes, int n_in,
                              void* d_out, int out_size, void* d_ws, size_t ws_size,
                              hipStream_t stream) {
    const float* z = (const float*)d_in[0];
    const float* W = (const float*)d_in[1];
    const float* b = (const float*)d_in[2];
    float* out  = (float*)d_out;
    const int N = in_sizes[0] / D_DIM;           // 8192

    float*    part = (float*)d_ws;                                  // 33.5 MB
    _Float16* Wf0  = (_Float16*)((char*)d_ws + ((size_t)64 << 20)); // 512 KB
    _Float16* Wf1  = Wf0 + (size_t)K_DIM * D_DIM;                   // 512 KB

    prep_w     <<<dim3((K_DIM * D_DIM / 4) / 256), dim3(256), 0, stream>>>(W, Wf0, Wf1);
    gemm_nobar <<<dim3((N / BM) * KQ), dim3(BLOCK), 0, stream>>>(z, Wf0, Wf1, part, N);
    reduce_topk<<<dim3(N / RG2),       dim3(BLK2), 0, stream>>>(part, b, out, N);
}

// Round 9
// 211.361 us; speedup vs baseline: 1.2122x; 1.0191x over previous
//
#include <hip/hip_runtime.h>
#include <math.h>

// Router: logits = z @ W^T + b ; top-2 sparse softmax.  z:[8192,4096]f32,
// W:[64,4096]f32, b:[64], k=2.
//
// R9: z fully register-resident per block-slice. R4/R5/R8 post-mortem:
// gemm stuck at ~76-86us across three structures with all pipes idle;
// common factor = shallow (2-deep) z pipeline -> latency exposure. Now each
// lane issues ALL 16 float4 z loads for its K-slice at kernel entry (256
// B/lane, 64 VGPRs; 2 blocks/CU x 16 waves = 256 KB/CU in flight >> 9 KB
// latency-BW product) -> z is pure throughput. W limbs (prep_w) staged to
// LDS once (67.6 KB, stride 264 f16 = 4 words mod 32 -> 2-way b128 reads,
// free); ONE barrier total. launch_bounds(512,4): VGPR budget 128, audit
// ~122. K-loop: regs -> RNE fp16 hi/lo limbs -> 12 MFMA/step x 8 steps.
// Precision identical to passing R5-R8: x = h + l*2^-11, 3 MFMA passes,
// recombine *2^-11 -> fp32-class logit error.
// Frag layouts (verified R4-R8): A[m=lane&15][k=quad*8+j],
// B[n=lane&15][k=quad*8+j], D[row=quad*4+reg][col=lane&15].

typedef _Float16 f16x8 __attribute__((ext_vector_type(8)));
typedef _Float16 f16x4 __attribute__((ext_vector_type(4)));
typedef float    f32x4 __attribute__((ext_vector_type(4)));

constexpr int D_DIM  = 4096;
constexpr int K_DIM  = 64;
constexpr int BM     = 128;            // rows per block (8 waves x 16)
constexpr int KQ     = 16;             // split-K across blocks
constexpr int KRANGE = D_DIM / KQ;     // 256
constexpr int BLOCK  = 512;
constexpr int BSTR   = 264;            // W limb row stride in f16 (528 B)

// ---- prep: W (fp32) -> f16 hi/lo limb planes in d_ws, layout [n][k] -------
__global__ __launch_bounds__(256) void prep_w(
    const float* __restrict__ W, _Float16* __restrict__ Wf0,
    _Float16* __restrict__ Wf1)
{
    int f = blockIdx.x * 256 + threadIdx.x;          // float4 index, 65536 total
    const float4 v = *(const float4*)(W + (long)f * 4);
    const float* p = (const float*)&v;
    f16x4 h, l;
#pragma unroll
    for (int j = 0; j < 4; ++j) {
        _Float16 hh = (_Float16)p[j];
        h[j] = hh;
        l[j] = (_Float16)((p[j] - (float)hh) * 2048.0f);
    }
    *(f16x4*)(Wf0 + (long)f * 4) = h;
    *(f16x4*)(Wf1 + (long)f * 4) = l;
}

// ---- gemm: z K-slice fully in registers, W limbs in LDS, one barrier ------
__global__ __launch_bounds__(BLOCK, 4) void gemm_zreg(
    const float* __restrict__ z, const _Float16* __restrict__ Wf0,
    const _Float16* __restrict__ Wf1, float* __restrict__ part, int N)
{
    __shared__ __align__(16) _Float16 Bs[2][K_DIM][BSTR];   // 67.6 KB

    const int tid  = threadIdx.x;
    const int lane = tid & 63;
    const int wv   = tid >> 6;          // 0..7 = m-tile (16 rows each)
    const int m16  = lane & 15;
    const int quad = lane >> 4;

    const int rgrp  = blockIdx.x >> 4;  // row group of 128
    const int kq    = blockIdx.x & 15;
    const long m0   = (long)rgrp * BM;
    const int kbase = kq * KRANGE;

    // issue ALL z loads for this lane's K-slice first (16 independent float4)
    const float* zp = z + (m0 + wv * 16 + m16) * (long)D_DIM + kbase;
    float4 za[16];
#pragma unroll
    for (int s = 0; s < 8; ++s) {
        za[s * 2 + 0] = *(const float4*)(zp + s * 32 + quad * 8);
        za[s * 2 + 1] = *(const float4*)(zp + s * 32 + quad * 8 + 4);
    }

    // stage W limb slice once: 2 planes x 64 rows x 256 f16 (4096 x 16B)
#pragma unroll
    for (int i = 0; i < 8; ++i) {
        int f  = tid + i * BLOCK;
        int p  = f >> 11;               // plane (i<4 -> 0, else 1)
        int rr = (f >> 5) & 63;
        int c  = f & 31;
        const _Float16* src = (p ? Wf1 : Wf0) + (long)rr * D_DIM + kbase + c * 8;
        *(f16x8*)&Bs[p][rr][c * 8] = *(const f16x8*)src;
    }
    __syncthreads();                    // the only barrier (z regs ready too)

    f32x4 acch[4], accl[4];
#pragma unroll
    for (int nt = 0; nt < 4; ++nt) {
        acch[nt] = (f32x4){0.f, 0.f, 0.f, 0.f};
        accl[nt] = (f32x4){0.f, 0.f, 0.f, 0.f};
    }

#pragma unroll
    for (int s = 0; s < 8; ++s) {       // 8 ks-steps, zero barriers
        f16x8 ah, al;
        const float* pz = (const float*)&za[s * 2];
#pragma unroll
        for (int j = 0; j < 8; ++j) {   // exact RNE limb split (proven)
            _Float16 hh = (_Float16)pz[j];
            ah[j] = hh;
            al[j] = (_Float16)((pz[j] - (float)hh) * 2048.0f);
        }
        const int ko = s * 32 + quad * 8;
#pragma unroll
        for (int nt = 0; nt < 4; ++nt) {
            const f16x8 bh = *(const f16x8*)&Bs[0][nt * 16 + m16][ko];
            const f16x8 bl = *(const f16x8*)&Bs[1][nt * 16 + m16][ko];
            accl[nt] = __builtin_amdgcn_mfma_f32_16x16x32_f16(al, bh, accl[nt], 0, 0, 0);
            accl[nt] = __builtin_amdgcn_mfma_f32_16x16x32_f16(ah, bl, accl[nt], 0, 0, 0);
            acch[nt] = __builtin_amdgcn_mfma_f32_16x16x32_f16(ah, bh, acch[nt], 0, 0, 0);
        }
    }

    // partial store: D[row=quad*4+r][col=m16], recombine limbs (*2^-11)
#pragma unroll
    for (int nt = 0; nt < 4; ++nt) {
#pragma unroll
        for (int r = 0; r < 4; ++r) {
            long row = m0 + wv * 16 + quad * 4 + r;
            part[((long)kq * N + row) * K_DIM + nt * 16 + m16] =
                acch[nt][r] + accl[nt][r] * 4.8828125e-4f;
        }
    }
}

// ---- reduce + bias + top-2 + sparse softmax -------------------------------
constexpr int RG2  = 32;
constexpr int BLK2 = 256;

__global__ __launch_bounds__(BLK2) void reduce_topk(
    const float* __restrict__ part, const float* __restrict__ bias,
    float* __restrict__ out, int N)
{
    __shared__ float lg[RG2][K_DIM + 1];
    __shared__ float sa1[RG2], sa2[RG2];
    __shared__ int   si1[RG2], si2[RG2];

    const int tid = threadIdx.x;
    const long r0 = (long)blockIdx.x * RG2;

#pragma unroll
    for (int i = 0; i < (RG2 * K_DIM) / (BLK2 * 4); ++i) {       // 2 iters
        int f = tid + i * BLK2, r = f >> 4, c4 = (f & 15) * 4;
        float4 s = *(const float4*)(part + (r0 + r) * K_DIM + c4);
#pragma unroll
        for (int q = 1; q < KQ; ++q) {
            const float4 v = *(const float4*)(part + ((long)q * N + r0 + r) * K_DIM + c4);
            s.x += v.x; s.y += v.y; s.z += v.z; s.w += v.w;
        }
        const float4 bv = *(const float4*)(bias + c4);
        lg[r][c4 + 0] = s.x + bv.x;
        lg[r][c4 + 1] = s.y + bv.y;
        lg[r][c4 + 2] = s.z + bv.z;
        lg[r][c4 + 3] = s.w + bv.w;
    }
    __syncthreads();

    if (tid < RG2) {   // strict >, ascending scan = lowest-index tie-break
        float m1 = -INFINITY, m2 = -INFINITY;
        int i1 = 0, i2 = 0;
        for (int j = 0; j < K_DIM; ++j) {
            float v = lg[tid][j];
            if (v > m1)      { m2 = m1; i2 = i1; m1 = v; i1 = j; }
            else if (v > m2) { m2 = v; i2 = j; }
        }
        float e2  = expf(m2 - m1);
        float inv = 1.f / (1.f + e2);
        sa1[tid] = inv; sa2[tid] = e2 * inv;
        si1[tid] = i1;  si2[tid] = i2;
    }
    __syncthreads();

    float* obase = out + r0 * K_DIM;
#pragma unroll
    for (int i = 0; i < (RG2 * K_DIM) / (BLK2 * 4); ++i) {       // 2 iters
        int f = tid + i * BLK2, r = f >> 4, j = (f & 15) * 4;
        int i1 = si1[r], i2 = si2[r];
        float a1 = sa1[r], a2 = sa2[r];
        float4 v;
        v.x = (j + 0 == i1) ? a1 : ((j + 0 == i2) ? a2 : 0.f);
        v.y = (j + 1 == i1) ? a1 : ((j + 1 == i2) ? a2 : 0.f);
        v.z = (j + 2 == i1) ? a1 : ((j + 2 == i2) ? a2 : 0.f);
        v.w = (j + 3 == i1) ? a1 : ((j + 3 == i2) ? a2 : 0.f);
        *(float4*)(obase + (long)r * K_DIM + j) = v;
    }
}

extern "C" void kernel_launch(void* const* d_in, const int* in_sizes, int n_in,
                              void* d_out, int out_size, void* d_ws, size_t ws_size,
                              hipStream_t stream) {
    const float* z = (const float*)d_in[0];
    const float* W = (const float*)d_in[1];
    const float* b = (const float*)d_in[2];
    float* out  = (float*)d_out;
    const int N = in_sizes[0] / D_DIM;           // 8192

    float*    part = (float*)d_ws;                                  // 33.5 MB
    _Float16* Wf0  = (_Float16*)((char*)d_ws + ((size_t)64 << 20)); // 512 KB
    _Float16* Wf1  = Wf0 + (size_t)K_DIM * D_DIM;                   // 512 KB

    prep_w     <<<dim3((K_DIM * D_DIM / 4) / 256), dim3(256), 0, stream>>>(W, Wf0, Wf1);
    gemm_zreg  <<<dim3((N / BM) * KQ), dim3(BLOCK), 0, stream>>>(z, Wf0, Wf1, part, N);
    reduce_topk<<<dim3(N / RG2),       dim3(BLK2), 0, stream>>>(part, b, out, N);
}